// Round 3
// baseline (615.609 us; speedup 1.0000x reference)
//
#include <hip/hip_runtime.h>
#include <stdint.h>

// RPN rotated-NMS post-processor, MI355X. Round 3: pair-compaction for IoU
// (circle-test ballot -> compact list -> dense clip), register-resident NMS.

#define NBATCH 4
#define AANCH 15
#define HDIM 200
#define WDIM 200
#define MTOT (AANCH*HDIM*WDIM)   // 600000
#define KTOP 1000
#define POSTN 300
#define NBINS 16384
#define CAND_CAP 4096
#define NWORDS 16                // ceil(1000/64)
#define NMS_TH 0.7f
#define BPB 75                   // blocks per batch for hist
#define CHUNK (MTOT/BPB)         // 8000
#define PAIR_CAP 262144

// ---------------- ws layout ----------------
constexpr size_t OFF_HIST = 0;
constexpr size_t SZ_HIST  = (size_t)NBATCH*NBINS*4;                 // 262144
constexpr size_t OFF_CNT  = OFF_HIST + SZ_HIST;   // cnt[4]; pcnt at +128
constexpr size_t OFF_THR  = OFF_CNT + 256;
constexpr size_t OFF_CAND = OFF_THR + 256;
constexpr size_t OFF_TOPK = OFF_CAND + (size_t)NBATCH*CAND_CAP*8;
constexpr size_t OFF_PROP = OFF_TOPK + (size_t)NBATCH*KTOP*8;
constexpr size_t OFF_SCORE= OFF_PROP + (size_t)NBATCH*KTOP*5*4;
constexpr size_t OFF_CORN = OFF_SCORE+ (size_t)NBATCH*KTOP*4;
constexpr size_t OFF_AREA = OFF_CORN + (size_t)NBATCH*KTOP*8*4;
constexpr size_t OFF_VALID= OFF_AREA + (size_t)NBATCH*KTOP*4;
constexpr size_t OFF_XYR  = OFF_VALID+ (size_t)NBATCH*KTOP*4;
constexpr size_t OFF_MASK = OFF_XYR  + (size_t)NBATCH*KTOP*16;
constexpr size_t SZ_MASK  = (size_t)NBATCH*KTOP*NWORDS*8;           // 512000
constexpr size_t OFF_KEEP = OFF_MASK + SZ_MASK;
constexpr size_t OFF_PLIST= OFF_KEEP + 512;

__device__ __forceinline__ float sigmoid_ref(float x) {
  return 1.0f / (1.0f + expf(-x));
}

// ---------------- histogram: LDS-privatized ----------------
__global__ __launch_bounds__(256) void k_hist(const float* __restrict__ obj,
                                              uint32_t* __restrict__ hist) {
  __shared__ uint32_t h[NBINS];
  for (int i = threadIdx.x; i < NBINS; i += 256) h[i] = 0;
  __syncthreads();
  int n = blockIdx.x / BPB, c = blockIdx.x % BPB;
  const float4* p = (const float4*)(obj + (size_t)n*MTOT + (size_t)c*CHUNK);
  const int nq = CHUNK/4;
  for (int q = threadIdx.x; q < nq; q += 256) {
    float4 v = p[q];
    #pragma unroll
    for (int k = 0; k < 4; ++k) {
      float x = (&v.x)[k];
      uint32_t bits = __float_as_uint(sigmoid_ref(x));
      uint32_t bin = bits >> 16; if (bin > NBINS-1) bin = NBINS-1;
      atomicAdd(&h[bin], 1u);
    }
  }
  __syncthreads();
  for (int i = threadIdx.x; i < NBINS; i += 256) {
    uint32_t v = h[i];
    if (v) atomicAdd(&hist[n*NBINS + i], v);
  }
}

// ---------------- threshold ----------------
__global__ __launch_bounds__(256) void k_thresh(const uint32_t* __restrict__ hist,
                                                uint32_t* __restrict__ thr) {
  __shared__ uint32_t ps[256];
  int n = blockIdx.x, tid = threadIdx.x;
  uint32_t s = 0;
  const uint32_t* hb = &hist[n*NBINS];
  #pragma unroll 4
  for (int b = tid*64; b < tid*64+64; ++b) s += hb[b];
  ps[tid] = s;
  __syncthreads();
  if (tid == 0) {
    uint32_t cum = 0; int cidx = -1;
    for (int cc = 255; cc >= 0; --cc) {
      if (cum + ps[cc] >= KTOP) { cidx = cc; break; }
      cum += ps[cc];
    }
    if (cidx < 0) { thr[n] = 0u; return; }
    int b = cidx*64+63;
    for (; b >= cidx*64; --b) { cum += hb[b]; if (cum >= KTOP) break; }
    thr[n] = (uint32_t)(b < 0 ? 0 : b);
  }
}

// ---------------- compact candidates ----------------
__global__ __launch_bounds__(256) void k_compact(const float* __restrict__ obj,
                                                 const uint32_t* __restrict__ thr,
                                                 uint64_t* __restrict__ cand,
                                                 uint32_t* __restrict__ cnt) {
  int t = blockIdx.x*blockDim.x + threadIdx.x;
  if (t >= NBATCH*MTOT) return;
  int n = t / MTOT;
  int rem = t % MTOT;
  float x = obj[t];
  uint32_t bits = __float_as_uint(sigmoid_ref(x));
  uint32_t bin = bits >> 16; if (bin > NBINS-1) bin = NBINS-1;
  if (bin >= thr[n]) {
    int hw = rem % (HDIM*WDIM);
    int a  = rem / (HDIM*WDIM);
    uint32_t fidx = (uint32_t)(hw*AANCH + a);
    uint32_t p = atomicAdd(&cnt[n], 1u);
    if (p < CAND_CAP)
      cand[(size_t)n*CAND_CAP + p] = ((uint64_t)bits << 32) | (uint32_t)(~fidx);
  }
}

// ---------------- bitonic sort ----------------
__global__ __launch_bounds__(1024) void k_sort(const uint64_t* __restrict__ cand,
                                               const uint32_t* __restrict__ cnt,
                                               uint64_t* __restrict__ topk) {
  __shared__ uint64_t sk[CAND_CAP];
  int n = blockIdx.x, tid = threadIdx.x;
  uint32_t c = cnt[n]; if (c > CAND_CAP) c = CAND_CAP;
  for (int i = tid; i < CAND_CAP; i += 1024)
    sk[i] = (i < (int)c) ? cand[(size_t)n*CAND_CAP + i] : 0ull;
  __syncthreads();
  for (int len = 2; len <= CAND_CAP; len <<= 1) {
    for (int str = len >> 1; str > 0; str >>= 1) {
      for (int i = tid; i < CAND_CAP; i += 1024) {
        int j = i ^ str;
        if (j > i) {
          bool up = ((i & len) == 0);
          uint64_t x = sk[i], y = sk[j];
          if ((x > y) == up) { sk[i] = y; sk[j] = x; }
        }
      }
      __syncthreads();
    }
  }
  for (int k = tid; k < KTOP; k += 1024)
    topk[(size_t)n*KTOP + k] = sk[CAND_CAP-1-k];
}

// ---------------- decode + corners + quick-reject metadata ----------------
__global__ void k_decode(const float* __restrict__ breg, const float* __restrict__ anch,
                         const uint64_t* __restrict__ topk,
                         float* __restrict__ prop, float* __restrict__ score,
                         float* __restrict__ corn, float* __restrict__ area,
                         float4* __restrict__ xyr, uint32_t* __restrict__ validf) {
#pragma clang fp contract(off)
  int t = blockIdx.x*blockDim.x + threadIdx.x;
  if (t >= NBATCH*KTOP) return;
  int n = t / KTOP;
  uint64_t key = topk[t];
  uint32_t idx = ~(uint32_t)(key & 0xFFFFFFFFull);
  float s = __uint_as_float((uint32_t)(key >> 32));
  int a = idx % AANCH, pos = idx / AANCH;
  int w = pos % WDIM, h = pos / WDIM;
  float d[5], an[5];
  #pragma unroll
  for (int j = 0; j < 5; ++j)
    d[j] = breg[((n*(AANCH*5) + (a*5+j))*HDIM + h)*WDIM + w];
  #pragma unroll
  for (int j = 0; j < 5; ++j)
    an[j] = anch[((size_t)n*MTOT + idx)*5 + j];
  const float CLIP = 4.135166556742356f;           // log(1000/16)
  float dw = fminf(d[2], CLIP), dh = fminf(d[3], CLIP);
  float x  = d[0]*an[2] + an[0];
  float y  = d[1]*an[3] + an[1];
  float bw = expf(dw)*an[2];
  float bh = expf(dh)*an[3];
  float th = an[4] + d[4]*57.29577951308232f;      // 180/pi
  prop[t*5+0]=x; prop[t*5+1]=y; prop[t*5+2]=bw; prop[t*5+3]=bh; prop[t*5+4]=th;
  score[t] = s;
  validf[t] = (bw >= 4.0f && bh >= 4.0f) ? 1u : 0u;
  area[t] = bw*bh;
  float r = 0.5f*sqrtf(bw*bw + bh*bh);
  xyr[t] = make_float4(x, y, r, 0.0f);
  float ang = th * 0.017453292519943295f;          // pi/180
  float cs = cosf(ang), sn = sinf(ang);
  float hw2 = bw*0.5f, hh2 = bh*0.5f;
  const float sx[4] = {1.f,-1.f,-1.f,1.f};
  const float sy[4] = {1.f,1.f,-1.f,-1.f};
  #pragma unroll
  for (int k = 0; k < 4; ++k) {
    float dxk = sx[k]*hw2, dyk = sy[k]*hh2;
    float cx = (x + cs*dxk) - sn*dyk;
    float cy = (y + sn*dxk) + cs*dyk;
    corn[t*8 + k*2 + 0] = cx;
    corn[t*8 + k*2 + 1] = cy;
  }
}

// ---------------- Sutherland-Hodgman (mirrors reference arithmetic) ----------------
__device__ float quad_inter_area(const float* __restrict__ ca, const float* __restrict__ cb) {
#pragma clang fp contract(off)
  float px[8], py[8];
  int n = 4;
  #pragma unroll
  for (int i = 0; i < 4; ++i) { px[i] = ca[2*i]; py[i] = ca[2*i+1]; }
  for (int e = 0; e < 4; ++e) {
    float p1x = cb[2*e], p1y = cb[2*e+1];
    int e2 = (e+1)&3;
    float dx = cb[2*e2] - p1x, dy = cb[2*e2+1] - p1y;
    float sd[8];
    for (int i = 0; i < n; ++i)
      sd[i] = dx*(py[i]-p1y) - dy*(px[i]-p1x);
    float qx[8], qy[8];
    int m = 0;
    for (int i = 0; i < n; ++i) {
      int nx = (i+1 < n) ? i+1 : 0;
      bool ini = sd[i] >= 0.0f, inn = sd[nx] >= 0.0f;
      if (ini) { qx[m]=px[i]; qy[m]=py[i]; ++m; }
      if (ini != inn) {
        float den = sd[i]-sd[nx];
        float dd = (fabsf(den) < 1e-12f) ? 1e-12f : den;
        float tt = sd[i]/dd;
        qx[m] = px[i] + tt*(px[nx]-px[i]);
        qy[m] = py[i] + tt*(py[nx]-py[i]);
        ++m;
      }
    }
    n = m;
    for (int i = 0; i < n; ++i) { px[i]=qx[i]; py[i]=qy[i]; }
    if (n == 0) break;
  }
  float ssum = 0.0f;
  for (int i = 0; i < n; ++i) {
    int nx = (i+1 < n) ? i+1 : 0;
    ssum += px[i]*py[nx] - px[nx]*py[i];
  }
  return 0.5f*fabsf(ssum);
}

// ---------------- phase A: circle test + ballot compaction ----------------
__global__ __launch_bounds__(256) void k_pairs(const float4* __restrict__ xyr,
                                               uint32_t* __restrict__ plist,
                                               uint32_t* __restrict__ pcnt,
                                               const float* __restrict__ corn,
                                               const float* __restrict__ area,
                                               uint64_t* __restrict__ mask) {
  int gw = blockIdx.x*4 + (threadIdx.x>>6);
  int lane = threadIdx.x & 63;
  if (gw >= NBATCH*KTOP*NWORDS) return;
  int n   = gw / (KTOP*NWORDS);
  int rem = gw % (KTOP*NWORDS);
  int i   = rem / NWORDS;
  int jb  = rem % NWORDS;
  if (jb*64 + 63 <= i) return;             // no j > i in this word
  int j = jb*64 + lane;
  bool hit = false;
  if (j > i && j < KTOP) {
    float4 a = xyr[n*KTOP + i];            // wave-uniform -> scalar load
    float4 b = xyr[n*KTOP + j];            // coalesced 16B/lane
    float dx = a.x - b.x, dy = a.y - b.y;
    float rs = a.z + b.z;
    hit = (dx*dx + dy*dy) <= rs*rs*1.0001f;
  }
  unsigned long long bal = __ballot(hit);
  if (!bal) return;
  int tot = __popcll(bal);
  int leader = __ffsll(bal) - 1;
  uint32_t base = 0;
  if (lane == leader) base = atomicAdd(pcnt, (uint32_t)tot);
  base = __shfl(base, leader);
  if (base + (uint32_t)tot <= PAIR_CAP) {
    if (hit) {
      int pos = __popcll(bal & ((1ull << lane) - 1ull));
      plist[base + pos] = ((uint32_t)n << 20) | ((uint32_t)i << 10) | (uint32_t)j;
    }
  } else {
    // overflow fallback: inline clip (correct, never expected)
    if (hit) {
      int bi = n*KTOP + i, bj = n*KTOP + j;
      float inter = quad_inter_area(&corn[(size_t)bi*8], &corn[(size_t)bj*8]);
      float uni = (area[bi] + area[bj]) - inter;
      if (inter / fmaxf(uni, 1e-8f) > NMS_TH)
        atomicOr((unsigned long long*)&mask[((size_t)n*KTOP + i)*NWORDS + jb],
                 1ull << lane);
    }
  }
}

// ---------------- phase B: dense clip over compacted pairs ----------------
__global__ __launch_bounds__(256) void k_clip(const uint32_t* __restrict__ plist,
                                              const uint32_t* __restrict__ pcnt,
                                              const float* __restrict__ corn,
                                              const float* __restrict__ area,
                                              uint64_t* __restrict__ mask) {
  uint32_t cnt = *pcnt; if (cnt > PAIR_CAP) cnt = PAIR_CAP;
  for (uint32_t t = blockIdx.x*blockDim.x + threadIdx.x; t < cnt;
       t += gridDim.x*blockDim.x) {
    uint32_t code = plist[t];
    int n = code >> 20, i = (code >> 10) & 1023, j = code & 1023;
    int bi = n*KTOP + i, bj = n*KTOP + j;
    float inter = quad_inter_area(&corn[(size_t)bi*8], &corn[(size_t)bj*8]);
    float uni = (area[bi] + area[bj]) - inter;
    if (inter / fmaxf(uni, 1e-8f) > NMS_TH)
      atomicOr((unsigned long long*)&mask[((size_t)n*KTOP + i)*NWORDS + (j>>6)],
               1ull << (j & 63));
  }
}

// ---------------- greedy NMS: mask in LDS, keep-words in one wave's registers ----------------
__global__ __launch_bounds__(256) void k_nms(const uint32_t* __restrict__ validf,
                                             const uint64_t* __restrict__ mask,
                                             uint64_t* __restrict__ keep) {
  __shared__ uint64_t sm[KTOP*NWORDS];   // 128000 B
  int n = blockIdx.x, tid = threadIdx.x;
  const uint4* s4 = (const uint4*)&mask[(size_t)n*KTOP*NWORDS];
  uint4* d4 = (uint4*)sm;
  for (int q = tid; q < KTOP*NWORDS/2; q += 256) d4[q] = s4[q];
  __syncthreads();
  if (tid >= 64) return;
  int lane = tid;
  // build valid bit-words: 16 coalesced loads + ballots
  uint64_t kwreg = 0;
  #pragma unroll
  for (int w = 0; w < NWORDS; ++w) {
    int k = w*64 + lane;
    uint32_t v = (k < KTOP) ? validf[n*KTOP + k] : 0u;
    unsigned long long b = __ballot(v != 0u);
    if (lane == w) kwreg = (uint64_t)b;
  }
  // serial greedy scan, rows prefetched 8-deep from LDS
  for (int i0 = 0; i0 < KTOP; i0 += 8) {
    uint64_t rr[8];
    #pragma unroll
    for (int u = 0; u < 8; ++u)
      rr[u] = (lane < NWORDS) ? sm[(i0+u)*NWORDS + lane] : 0ull;
    #pragma unroll
    for (int u = 0; u < 8; ++u) {
      int i = i0 + u;
      uint64_t w = __shfl(kwreg, i >> 6);
      if ((w >> (i & 63)) & 1ull) kwreg &= ~rr[u];
    }
  }
  // rank <= POSTN trim, uniform across lanes
  int prev = 0;
  #pragma unroll
  for (int t = 0; t < NWORDS; ++t) {
    uint64_t wrd = __shfl(kwreg, t);
    int pc = __popcll(wrd);
    if (prev >= POSTN) wrd = 0;
    else if (prev + pc > POSTN) {
      int allow = POSTN - prev;
      while (__popcll(wrd) > allow) wrd &= ~(1ull << (63 - __clzll(wrd)));
    }
    prev += __popcll(wrd);
    if (lane == 0) keep[n*NWORDS + t] = wrd;
  }
}

__global__ void k_out(const float* __restrict__ prop, const float* __restrict__ score,
                      const uint64_t* __restrict__ keep, float* __restrict__ out) {
  int t = blockIdx.x*blockDim.x + threadIdx.x;
  if (t >= NBATCH*KTOP) return;
  int n = t / KTOP, k = t % KTOP;
  bool b = (keep[n*NWORDS + (k>>6)] >> (k&63)) & 1ull;
  float f = b ? 1.0f : 0.0f;
  #pragma unroll
  for (int c = 0; c < 5; ++c) out[t*6 + c] = prop[t*5 + c] * f;
  out[t*6 + 5] = score[t] * f;
}

extern "C" void kernel_launch(void* const* d_in, const int* in_sizes, int n_in,
                              void* d_out, int out_size, void* d_ws, size_t ws_size,
                              hipStream_t stream) {
  const float* obj  = (const float*)d_in[0];
  const float* breg = (const float*)d_in[1];
  const float* anch = (const float*)d_in[2];
  float* out = (float*)d_out;
  char* ws = (char*)d_ws;

  uint32_t* hist  = (uint32_t*)(ws + OFF_HIST);
  uint32_t* cnt   = (uint32_t*)(ws + OFF_CNT);
  uint32_t* pcnt  = (uint32_t*)(ws + OFF_CNT + 128);
  uint32_t* thr   = (uint32_t*)(ws + OFF_THR);
  uint64_t* cand  = (uint64_t*)(ws + OFF_CAND);
  uint64_t* topk  = (uint64_t*)(ws + OFF_TOPK);
  float*    prop  = (float*)(ws + OFF_PROP);
  float*    score = (float*)(ws + OFF_SCORE);
  float*    corn  = (float*)(ws + OFF_CORN);
  float*    area  = (float*)(ws + OFF_AREA);
  uint32_t* validf= (uint32_t*)(ws + OFF_VALID);
  float4*   xyr   = (float4*)(ws + OFF_XYR);
  uint64_t* mask  = (uint64_t*)(ws + OFF_MASK);
  uint64_t* keep  = (uint64_t*)(ws + OFF_KEEP);
  uint32_t* plist = (uint32_t*)(ws + OFF_PLIST);

  hipMemsetAsync(ws, 0, OFF_CAND, stream);            // hist + cnt + pcnt (+thr)
  hipMemsetAsync(ws + OFF_MASK, 0, SZ_MASK, stream);  // suppression mask

  int nt = NBATCH*MTOT;
  k_hist   <<<NBATCH*BPB, 256, 0, stream>>>(obj, hist);
  k_thresh <<<NBATCH, 256, 0, stream>>>(hist, thr);
  k_compact<<<(nt+255)/256, 256, 0, stream>>>(obj, thr, cand, cnt);
  k_sort   <<<NBATCH, 1024, 0, stream>>>(cand, cnt, topk);
  k_decode <<<(NBATCH*KTOP+255)/256, 256, 0, stream>>>(breg, anch, topk, prop, score, corn, area, xyr, validf);
  k_pairs  <<<NBATCH*KTOP*NWORDS/4, 256, 0, stream>>>(xyr, plist, pcnt, corn, area, mask);
  k_clip   <<<1024, 256, 0, stream>>>(plist, pcnt, corn, area, mask);
  k_nms    <<<NBATCH, 256, 0, stream>>>(validf, mask, keep);
  k_out    <<<(NBATCH*KTOP+255)/256, 256, 0, stream>>>(prop, score, keep, out);
}

// Round 4
// 283.427 us; speedup vs baseline: 2.1720x; 2.1720x over previous
//
#include <hip/hip_runtime.h>
#include <stdint.h>

// RPN rotated-NMS post-processor, MI355X. Round 4: fused circle-test + clip
// with LDS work queue (kills the single-address global atomic chain of r3).

#define NBATCH 4
#define AANCH 15
#define HDIM 200
#define WDIM 200
#define MTOT (AANCH*HDIM*WDIM)   // 600000
#define KTOP 1000
#define POSTN 300
#define NBINS 16384
#define CAND_CAP 4096
#define NWORDS 16                // ceil(1000/64)
#define NMS_TH 0.7f
#define BPB 75                   // blocks per batch for hist
#define CHUNK (MTOT/BPB)         // 8000
#define IOU_BPB 125              // iou blocks per batch
#define IOU_WPB 128              // mask words per iou block (16000/125)
#define QCAP (IOU_WPB*64)        // 8192: provable max survivors per block

// ---------------- ws layout ----------------
constexpr size_t OFF_HIST = 0;
constexpr size_t SZ_HIST  = (size_t)NBATCH*NBINS*4;                 // 262144
constexpr size_t OFF_CNT  = OFF_HIST + SZ_HIST;
constexpr size_t OFF_THR  = OFF_CNT + 256;
constexpr size_t OFF_CAND = OFF_THR + 256;
constexpr size_t OFF_TOPK = OFF_CAND + (size_t)NBATCH*CAND_CAP*8;
constexpr size_t OFF_PROP = OFF_TOPK + (size_t)NBATCH*KTOP*8;
constexpr size_t OFF_SCORE= OFF_PROP + (size_t)NBATCH*KTOP*5*4;
constexpr size_t OFF_CORN = OFF_SCORE+ (size_t)NBATCH*KTOP*4;
constexpr size_t OFF_AREA = OFF_CORN + (size_t)NBATCH*KTOP*8*4;
constexpr size_t OFF_VALID= OFF_AREA + (size_t)NBATCH*KTOP*4;
constexpr size_t OFF_XYR  = OFF_VALID+ (size_t)NBATCH*KTOP*4;
constexpr size_t OFF_MASK = OFF_XYR  + (size_t)NBATCH*KTOP*16;
constexpr size_t SZ_MASK  = (size_t)NBATCH*KTOP*NWORDS*8;           // 512000
constexpr size_t OFF_KEEP = OFF_MASK + SZ_MASK;

__device__ __forceinline__ float sigmoid_ref(float x) {
  return 1.0f / (1.0f + expf(-x));
}

// ---------------- histogram: LDS-privatized ----------------
__global__ __launch_bounds__(256) void k_hist(const float* __restrict__ obj,
                                              uint32_t* __restrict__ hist) {
  __shared__ uint32_t h[NBINS];
  for (int i = threadIdx.x; i < NBINS; i += 256) h[i] = 0;
  __syncthreads();
  int n = blockIdx.x / BPB, c = blockIdx.x % BPB;
  const float4* p = (const float4*)(obj + (size_t)n*MTOT + (size_t)c*CHUNK);
  const int nq = CHUNK/4;
  for (int q = threadIdx.x; q < nq; q += 256) {
    float4 v = p[q];
    #pragma unroll
    for (int k = 0; k < 4; ++k) {
      float x = (&v.x)[k];
      uint32_t bits = __float_as_uint(sigmoid_ref(x));
      uint32_t bin = bits >> 16; if (bin > NBINS-1) bin = NBINS-1;
      atomicAdd(&h[bin], 1u);
    }
  }
  __syncthreads();
  for (int i = threadIdx.x; i < NBINS; i += 256) {
    uint32_t v = h[i];
    if (v) atomicAdd(&hist[n*NBINS + i], v);
  }
}

// ---------------- threshold ----------------
__global__ __launch_bounds__(256) void k_thresh(const uint32_t* __restrict__ hist,
                                                uint32_t* __restrict__ thr) {
  __shared__ uint32_t ps[256];
  int n = blockIdx.x, tid = threadIdx.x;
  uint32_t s = 0;
  const uint32_t* hb = &hist[n*NBINS];
  #pragma unroll 4
  for (int b = tid*64; b < tid*64+64; ++b) s += hb[b];
  ps[tid] = s;
  __syncthreads();
  if (tid == 0) {
    uint32_t cum = 0; int cidx = -1;
    for (int cc = 255; cc >= 0; --cc) {
      if (cum + ps[cc] >= KTOP) { cidx = cc; break; }
      cum += ps[cc];
    }
    if (cidx < 0) { thr[n] = 0u; return; }
    int b = cidx*64+63;
    for (; b >= cidx*64; --b) { cum += hb[b]; if (cum >= KTOP) break; }
    thr[n] = (uint32_t)(b < 0 ? 0 : b);
  }
}

// ---------------- compact candidates ----------------
__global__ __launch_bounds__(256) void k_compact(const float* __restrict__ obj,
                                                 const uint32_t* __restrict__ thr,
                                                 uint64_t* __restrict__ cand,
                                                 uint32_t* __restrict__ cnt) {
  int t = blockIdx.x*blockDim.x + threadIdx.x;
  if (t >= NBATCH*MTOT) return;
  int n = t / MTOT;
  int rem = t % MTOT;
  float x = obj[t];
  uint32_t bits = __float_as_uint(sigmoid_ref(x));
  uint32_t bin = bits >> 16; if (bin > NBINS-1) bin = NBINS-1;
  if (bin >= thr[n]) {
    int hw = rem % (HDIM*WDIM);
    int a  = rem / (HDIM*WDIM);
    uint32_t fidx = (uint32_t)(hw*AANCH + a);
    uint32_t p = atomicAdd(&cnt[n], 1u);
    if (p < CAND_CAP)
      cand[(size_t)n*CAND_CAP + p] = ((uint64_t)bits << 32) | (uint32_t)(~fidx);
  }
}

// ---------------- bitonic sort ----------------
__global__ __launch_bounds__(1024) void k_sort(const uint64_t* __restrict__ cand,
                                               const uint32_t* __restrict__ cnt,
                                               uint64_t* __restrict__ topk) {
  __shared__ uint64_t sk[CAND_CAP];
  int n = blockIdx.x, tid = threadIdx.x;
  uint32_t c = cnt[n]; if (c > CAND_CAP) c = CAND_CAP;
  for (int i = tid; i < CAND_CAP; i += 1024)
    sk[i] = (i < (int)c) ? cand[(size_t)n*CAND_CAP + i] : 0ull;
  __syncthreads();
  for (int len = 2; len <= CAND_CAP; len <<= 1) {
    for (int str = len >> 1; str > 0; str >>= 1) {
      for (int i = tid; i < CAND_CAP; i += 1024) {
        int j = i ^ str;
        if (j > i) {
          bool up = ((i & len) == 0);
          uint64_t x = sk[i], y = sk[j];
          if ((x > y) == up) { sk[i] = y; sk[j] = x; }
        }
      }
      __syncthreads();
    }
  }
  for (int k = tid; k < KTOP; k += 1024)
    topk[(size_t)n*KTOP + k] = sk[CAND_CAP-1-k];
}

// ---------------- decode + corners + quick-reject metadata ----------------
__global__ void k_decode(const float* __restrict__ breg, const float* __restrict__ anch,
                         const uint64_t* __restrict__ topk,
                         float* __restrict__ prop, float* __restrict__ score,
                         float* __restrict__ corn, float* __restrict__ area,
                         float4* __restrict__ xyr, uint32_t* __restrict__ validf) {
#pragma clang fp contract(off)
  int t = blockIdx.x*blockDim.x + threadIdx.x;
  if (t >= NBATCH*KTOP) return;
  int n = t / KTOP;
  uint64_t key = topk[t];
  uint32_t idx = ~(uint32_t)(key & 0xFFFFFFFFull);
  float s = __uint_as_float((uint32_t)(key >> 32));
  int a = idx % AANCH, pos = idx / AANCH;
  int w = pos % WDIM, h = pos / WDIM;
  float d[5], an[5];
  #pragma unroll
  for (int j = 0; j < 5; ++j)
    d[j] = breg[((n*(AANCH*5) + (a*5+j))*HDIM + h)*WDIM + w];
  #pragma unroll
  for (int j = 0; j < 5; ++j)
    an[j] = anch[((size_t)n*MTOT + idx)*5 + j];
  const float CLIP = 4.135166556742356f;           // log(1000/16)
  float dw = fminf(d[2], CLIP), dh = fminf(d[3], CLIP);
  float x  = d[0]*an[2] + an[0];
  float y  = d[1]*an[3] + an[1];
  float bw = expf(dw)*an[2];
  float bh = expf(dh)*an[3];
  float th = an[4] + d[4]*57.29577951308232f;      // 180/pi
  prop[t*5+0]=x; prop[t*5+1]=y; prop[t*5+2]=bw; prop[t*5+3]=bh; prop[t*5+4]=th;
  score[t] = s;
  validf[t] = (bw >= 4.0f && bh >= 4.0f) ? 1u : 0u;
  area[t] = bw*bh;
  float r = 0.5f*sqrtf(bw*bw + bh*bh);
  xyr[t] = make_float4(x, y, r, 0.0f);
  float ang = th * 0.017453292519943295f;          // pi/180
  float cs = cosf(ang), sn = sinf(ang);
  float hw2 = bw*0.5f, hh2 = bh*0.5f;
  const float sx[4] = {1.f,-1.f,-1.f,1.f};
  const float sy[4] = {1.f,1.f,-1.f,-1.f};
  #pragma unroll
  for (int k = 0; k < 4; ++k) {
    float dxk = sx[k]*hw2, dyk = sy[k]*hh2;
    float cx = (x + cs*dxk) - sn*dyk;
    float cy = (y + sn*dxk) + cs*dyk;
    corn[t*8 + k*2 + 0] = cx;
    corn[t*8 + k*2 + 1] = cy;
  }
}

// ---------------- Sutherland-Hodgman (mirrors reference arithmetic) ----------------
__device__ float quad_inter_area(const float* __restrict__ ca, const float* __restrict__ cb) {
#pragma clang fp contract(off)
  float px[8], py[8];
  int n = 4;
  #pragma unroll
  for (int i = 0; i < 4; ++i) { px[i] = ca[2*i]; py[i] = ca[2*i+1]; }
  for (int e = 0; e < 4; ++e) {
    float p1x = cb[2*e], p1y = cb[2*e+1];
    int e2 = (e+1)&3;
    float dx = cb[2*e2] - p1x, dy = cb[2*e2+1] - p1y;
    float sd[8];
    for (int i = 0; i < n; ++i)
      sd[i] = dx*(py[i]-p1y) - dy*(px[i]-p1x);
    float qx[8], qy[8];
    int m = 0;
    for (int i = 0; i < n; ++i) {
      int nx = (i+1 < n) ? i+1 : 0;
      bool ini = sd[i] >= 0.0f, inn = sd[nx] >= 0.0f;
      if (ini) { qx[m]=px[i]; qy[m]=py[i]; ++m; }
      if (ini != inn) {
        float den = sd[i]-sd[nx];
        float dd = (fabsf(den) < 1e-12f) ? 1e-12f : den;
        float tt = sd[i]/dd;
        qx[m] = px[i] + tt*(px[nx]-px[i]);
        qy[m] = py[i] + tt*(py[nx]-py[i]);
        ++m;
      }
    }
    n = m;
    for (int i = 0; i < n; ++i) { px[i]=qx[i]; py[i]=qy[i]; }
    if (n == 0) break;
  }
  float ssum = 0.0f;
  for (int i = 0; i < n; ++i) {
    int nx = (i+1 < n) ? i+1 : 0;
    ssum += px[i]*py[nx] - px[nx]*py[i];
  }
  return 0.5f*fabsf(ssum);
}

// ---------------- fused circle-test + clip with LDS work queue ----------------
// Block owns IOU_WPB consecutive mask words (8 i-rows x all j) of one batch.
// Scan: wave ballot -> LDS queue (max QCAP provable, no overflow path).
// Clip: all 256 threads drain the queue densely; scattered atomicOr to mask.
__global__ __launch_bounds__(256) void k_iou(const float4* __restrict__ xyr,
                                             const float* __restrict__ corn,
                                             const float* __restrict__ area,
                                             uint64_t* __restrict__ mask) {
  __shared__ uint32_t q[QCAP];       // 32 KB
  __shared__ uint32_t qcnt;
  int n = blockIdx.x / IOU_BPB;
  int wbase = (blockIdx.x % IOU_BPB) * IOU_WPB;
  int wv = threadIdx.x >> 6, lane = threadIdx.x & 63;
  if (threadIdx.x == 0) qcnt = 0;
  __syncthreads();
  for (int w = wv; w < IOU_WPB; w += 4) {
    int word = wbase + w;
    int i = word >> 4;               // word / NWORDS
    int jb = word & 15;              // word % NWORDS
    if (jb*64 + 63 <= i) continue;   // no j > i in this word
    int j = jb*64 + lane;
    bool hit = false;
    if (j > i && j < KTOP) {
      float4 a = xyr[n*KTOP + i];    // wave-uniform
      float4 b = xyr[n*KTOP + j];    // coalesced 16B/lane
      float dx = a.x - b.x, dy = a.y - b.y;
      float rs = a.z + b.z;
      hit = (dx*dx + dy*dy) <= rs*rs*1.0001f;
    }
    unsigned long long bal = __ballot(hit);
    if (!bal) continue;
    int tot = __popcll(bal);
    int leader = __ffsll(bal) - 1;
    uint32_t base = 0;
    if (lane == leader) base = atomicAdd(&qcnt, (uint32_t)tot);
    base = __shfl(base, leader);
    if (hit) {
      int pos = __popcll(bal & ((1ull << lane) - 1ull));
      q[base + pos] = ((uint32_t)i << 10) | (uint32_t)j;
    }
  }
  __syncthreads();
  uint32_t cnt = qcnt;
  for (uint32_t t = threadIdx.x; t < cnt; t += 256) {
    uint32_t code = q[t];
    int i = code >> 10, j = code & 1023;
    int bi = n*KTOP + i, bj = n*KTOP + j;
    float inter = quad_inter_area(&corn[(size_t)bi*8], &corn[(size_t)bj*8]);
    float uni = (area[bi] + area[bj]) - inter;
    if (inter / fmaxf(uni, 1e-8f) > NMS_TH)
      atomicOr((unsigned long long*)&mask[((size_t)n*KTOP + i)*NWORDS + (j>>6)],
               1ull << (j & 63));
  }
}

// ---------------- greedy NMS: mask in LDS, keep-words in one wave's registers ----------------
__global__ __launch_bounds__(256) void k_nms(const uint32_t* __restrict__ validf,
                                             const uint64_t* __restrict__ mask,
                                             uint64_t* __restrict__ keep) {
  __shared__ uint64_t sm[KTOP*NWORDS];   // 128000 B
  int n = blockIdx.x, tid = threadIdx.x;
  const uint4* s4 = (const uint4*)&mask[(size_t)n*KTOP*NWORDS];
  uint4* d4 = (uint4*)sm;
  for (int q = tid; q < KTOP*NWORDS/2; q += 256) d4[q] = s4[q];
  __syncthreads();
  if (tid >= 64) return;
  int lane = tid;
  uint64_t kwreg = 0;
  #pragma unroll
  for (int w = 0; w < NWORDS; ++w) {
    int k = w*64 + lane;
    uint32_t v = (k < KTOP) ? validf[n*KTOP + k] : 0u;
    unsigned long long b = __ballot(v != 0u);
    if (lane == w) kwreg = (uint64_t)b;
  }
  for (int i0 = 0; i0 < KTOP; i0 += 8) {
    uint64_t rr[8];
    #pragma unroll
    for (int u = 0; u < 8; ++u)
      rr[u] = (lane < NWORDS) ? sm[(i0+u)*NWORDS + lane] : 0ull;
    #pragma unroll
    for (int u = 0; u < 8; ++u) {
      int i = i0 + u;
      uint64_t w = __shfl(kwreg, i >> 6);
      if ((w >> (i & 63)) & 1ull) kwreg &= ~rr[u];
    }
  }
  int prev = 0;
  #pragma unroll
  for (int t = 0; t < NWORDS; ++t) {
    uint64_t wrd = __shfl(kwreg, t);
    int pc = __popcll(wrd);
    if (prev >= POSTN) wrd = 0;
    else if (prev + pc > POSTN) {
      int allow = POSTN - prev;
      while (__popcll(wrd) > allow) wrd &= ~(1ull << (63 - __clzll(wrd)));
    }
    prev += __popcll(wrd);
    if (lane == 0) keep[n*NWORDS + t] = wrd;
  }
}

__global__ void k_out(const float* __restrict__ prop, const float* __restrict__ score,
                      const uint64_t* __restrict__ keep, float* __restrict__ out) {
  int t = blockIdx.x*blockDim.x + threadIdx.x;
  if (t >= NBATCH*KTOP) return;
  int n = t / KTOP, k = t % KTOP;
  bool b = (keep[n*NWORDS + (k>>6)] >> (k&63)) & 1ull;
  float f = b ? 1.0f : 0.0f;
  #pragma unroll
  for (int c = 0; c < 5; ++c) out[t*6 + c] = prop[t*5 + c] * f;
  out[t*6 + 5] = score[t] * f;
}

extern "C" void kernel_launch(void* const* d_in, const int* in_sizes, int n_in,
                              void* d_out, int out_size, void* d_ws, size_t ws_size,
                              hipStream_t stream) {
  const float* obj  = (const float*)d_in[0];
  const float* breg = (const float*)d_in[1];
  const float* anch = (const float*)d_in[2];
  float* out = (float*)d_out;
  char* ws = (char*)d_ws;

  uint32_t* hist  = (uint32_t*)(ws + OFF_HIST);
  uint32_t* cnt   = (uint32_t*)(ws + OFF_CNT);
  uint32_t* thr   = (uint32_t*)(ws + OFF_THR);
  uint64_t* cand  = (uint64_t*)(ws + OFF_CAND);
  uint64_t* topk  = (uint64_t*)(ws + OFF_TOPK);
  float*    prop  = (float*)(ws + OFF_PROP);
  float*    score = (float*)(ws + OFF_SCORE);
  float*    corn  = (float*)(ws + OFF_CORN);
  float*    area  = (float*)(ws + OFF_AREA);
  uint32_t* validf= (uint32_t*)(ws + OFF_VALID);
  float4*   xyr   = (float4*)(ws + OFF_XYR);
  uint64_t* mask  = (uint64_t*)(ws + OFF_MASK);
  uint64_t* keep  = (uint64_t*)(ws + OFF_KEEP);

  hipMemsetAsync(ws, 0, OFF_CAND, stream);            // hist + cnt + thr
  hipMemsetAsync(ws + OFF_MASK, 0, SZ_MASK, stream);  // suppression mask

  int nt = NBATCH*MTOT;
  k_hist   <<<NBATCH*BPB, 256, 0, stream>>>(obj, hist);
  k_thresh <<<NBATCH, 256, 0, stream>>>(hist, thr);
  k_compact<<<(nt+255)/256, 256, 0, stream>>>(obj, thr, cand, cnt);
  k_sort   <<<NBATCH, 1024, 0, stream>>>(cand, cnt, topk);
  k_decode <<<(NBATCH*KTOP+255)/256, 256, 0, stream>>>(breg, anch, topk, prop, score, corn, area, xyr, validf);
  k_iou    <<<NBATCH*IOU_BPB, 256, 0, stream>>>(xyr, corn, area, mask);
  k_nms    <<<NBATCH, 256, 0, stream>>>(validf, mask, keep);
  k_out    <<<(NBATCH*KTOP+255)/256, 256, 0, stream>>>(prop, score, keep, out);
}

// Round 5
// 240.287 us; speedup vs baseline: 2.5620x; 1.1795x over previous
//
#include <hip/hip_runtime.h>
#include <stdint.h>

// RPN rotated-NMS post-processor, MI355X. Round 5: blocked greedy NMS
// (64-row diagonal serial resolve + parallel OR-reduced cross-block apply),
// wave-aggregated compaction atomics.

#define NBATCH 4
#define AANCH 15
#define HDIM 200
#define WDIM 200
#define MTOT (AANCH*HDIM*WDIM)   // 600000
#define KTOP 1000
#define POSTN 300
#define NBINS 16384
#define CAND_CAP 4096
#define NWORDS 16                // ceil(1000/64)
#define NMS_TH 0.7f
#define BPB 75                   // blocks per batch for hist
#define CHUNK (MTOT/BPB)         // 8000
#define IOU_BPB 125              // iou blocks per batch
#define IOU_WPB 128              // mask words per iou block (16000/125)
#define QCAP (IOU_WPB*64)        // 8192: provable max survivors per block

// ---------------- ws layout ----------------
constexpr size_t OFF_HIST = 0;
constexpr size_t SZ_HIST  = (size_t)NBATCH*NBINS*4;                 // 262144
constexpr size_t OFF_CNT  = OFF_HIST + SZ_HIST;
constexpr size_t OFF_THR  = OFF_CNT + 256;
constexpr size_t OFF_CAND = OFF_THR + 256;
constexpr size_t OFF_TOPK = OFF_CAND + (size_t)NBATCH*CAND_CAP*8;
constexpr size_t OFF_PROP = OFF_TOPK + (size_t)NBATCH*KTOP*8;
constexpr size_t OFF_SCORE= OFF_PROP + (size_t)NBATCH*KTOP*5*4;
constexpr size_t OFF_CORN = OFF_SCORE+ (size_t)NBATCH*KTOP*4;
constexpr size_t OFF_AREA = OFF_CORN + (size_t)NBATCH*KTOP*8*4;
constexpr size_t OFF_VALID= OFF_AREA + (size_t)NBATCH*KTOP*4;
constexpr size_t OFF_XYR  = OFF_VALID+ (size_t)NBATCH*KTOP*4;
constexpr size_t OFF_MASK = OFF_XYR  + (size_t)NBATCH*KTOP*16;
constexpr size_t SZ_MASK  = (size_t)NBATCH*KTOP*NWORDS*8;           // 512000
constexpr size_t OFF_KEEP = OFF_MASK + SZ_MASK;

__device__ __forceinline__ float sigmoid_ref(float x) {
  return 1.0f / (1.0f + expf(-x));
}

// ---------------- histogram: LDS-privatized ----------------
__global__ __launch_bounds__(256) void k_hist(const float* __restrict__ obj,
                                              uint32_t* __restrict__ hist) {
  __shared__ uint32_t h[NBINS];
  for (int i = threadIdx.x; i < NBINS; i += 256) h[i] = 0;
  __syncthreads();
  int n = blockIdx.x / BPB, c = blockIdx.x % BPB;
  const float4* p = (const float4*)(obj + (size_t)n*MTOT + (size_t)c*CHUNK);
  const int nq = CHUNK/4;
  for (int q = threadIdx.x; q < nq; q += 256) {
    float4 v = p[q];
    #pragma unroll
    for (int k = 0; k < 4; ++k) {
      float x = (&v.x)[k];
      uint32_t bits = __float_as_uint(sigmoid_ref(x));
      uint32_t bin = bits >> 16; if (bin > NBINS-1) bin = NBINS-1;
      atomicAdd(&h[bin], 1u);
    }
  }
  __syncthreads();
  for (int i = threadIdx.x; i < NBINS; i += 256) {
    uint32_t v = h[i];
    if (v) atomicAdd(&hist[n*NBINS + i], v);
  }
}

// ---------------- threshold ----------------
__global__ __launch_bounds__(256) void k_thresh(const uint32_t* __restrict__ hist,
                                                uint32_t* __restrict__ thr) {
  __shared__ uint32_t ps[256];
  int n = blockIdx.x, tid = threadIdx.x;
  uint32_t s = 0;
  const uint32_t* hb = &hist[n*NBINS];
  #pragma unroll 4
  for (int b = tid*64; b < tid*64+64; ++b) s += hb[b];
  ps[tid] = s;
  __syncthreads();
  if (tid == 0) {
    uint32_t cum = 0; int cidx = -1;
    for (int cc = 255; cc >= 0; --cc) {
      if (cum + ps[cc] >= KTOP) { cidx = cc; break; }
      cum += ps[cc];
    }
    if (cidx < 0) { thr[n] = 0u; return; }
    int b = cidx*64+63;
    for (; b >= cidx*64; --b) { cum += hb[b]; if (cum >= KTOP) break; }
    thr[n] = (uint32_t)(b < 0 ? 0 : b);
  }
}

// ---------------- compact candidates (wave-aggregated atomics) ----------------
__global__ __launch_bounds__(256) void k_compact(const float* __restrict__ obj,
                                                 const uint32_t* __restrict__ thr,
                                                 uint64_t* __restrict__ cand,
                                                 uint32_t* __restrict__ cnt) {
  int t = blockIdx.x*blockDim.x + threadIdx.x;
  if (t >= NBATCH*MTOT) return;
  int n = t / MTOT;           // wave-uniform: MTOT % 64 == 0
  int rem = t % MTOT;
  int lane = threadIdx.x & 63;
  float x = obj[t];
  uint32_t bits = __float_as_uint(sigmoid_ref(x));
  uint32_t bin = bits >> 16; if (bin > NBINS-1) bin = NBINS-1;
  bool hit = (bin >= thr[n]);
  unsigned long long bal = __ballot(hit);
  if (!bal) return;
  int tot = __popcll(bal);
  int leader = __ffsll(bal) - 1;
  uint32_t base = 0;
  if (lane == leader) base = atomicAdd(&cnt[n], (uint32_t)tot);
  base = __shfl(base, leader);
  if (hit) {
    uint32_t p = base + (uint32_t)__popcll(bal & ((1ull << lane) - 1ull));
    if (p < CAND_CAP) {
      int hw = rem % (HDIM*WDIM);
      int a  = rem / (HDIM*WDIM);
      uint32_t fidx = (uint32_t)(hw*AANCH + a);
      cand[(size_t)n*CAND_CAP + p] = ((uint64_t)bits << 32) | (uint32_t)(~fidx);
    }
  }
}

// ---------------- bitonic sort ----------------
__global__ __launch_bounds__(1024) void k_sort(const uint64_t* __restrict__ cand,
                                               const uint32_t* __restrict__ cnt,
                                               uint64_t* __restrict__ topk) {
  __shared__ uint64_t sk[CAND_CAP];
  int n = blockIdx.x, tid = threadIdx.x;
  uint32_t c = cnt[n]; if (c > CAND_CAP) c = CAND_CAP;
  for (int i = tid; i < CAND_CAP; i += 1024)
    sk[i] = (i < (int)c) ? cand[(size_t)n*CAND_CAP + i] : 0ull;
  __syncthreads();
  for (int len = 2; len <= CAND_CAP; len <<= 1) {
    for (int str = len >> 1; str > 0; str >>= 1) {
      for (int i = tid; i < CAND_CAP; i += 1024) {
        int j = i ^ str;
        if (j > i) {
          bool up = ((i & len) == 0);
          uint64_t x = sk[i], y = sk[j];
          if ((x > y) == up) { sk[i] = y; sk[j] = x; }
        }
      }
      __syncthreads();
    }
  }
  for (int k = tid; k < KTOP; k += 1024)
    topk[(size_t)n*KTOP + k] = sk[CAND_CAP-1-k];
}

// ---------------- decode + corners + quick-reject metadata ----------------
__global__ void k_decode(const float* __restrict__ breg, const float* __restrict__ anch,
                         const uint64_t* __restrict__ topk,
                         float* __restrict__ prop, float* __restrict__ score,
                         float* __restrict__ corn, float* __restrict__ area,
                         float4* __restrict__ xyr, uint32_t* __restrict__ validf) {
#pragma clang fp contract(off)
  int t = blockIdx.x*blockDim.x + threadIdx.x;
  if (t >= NBATCH*KTOP) return;
  int n = t / KTOP;
  uint64_t key = topk[t];
  uint32_t idx = ~(uint32_t)(key & 0xFFFFFFFFull);
  float s = __uint_as_float((uint32_t)(key >> 32));
  int a = idx % AANCH, pos = idx / AANCH;
  int w = pos % WDIM, h = pos / WDIM;
  float d[5], an[5];
  #pragma unroll
  for (int j = 0; j < 5; ++j)
    d[j] = breg[((n*(AANCH*5) + (a*5+j))*HDIM + h)*WDIM + w];
  #pragma unroll
  for (int j = 0; j < 5; ++j)
    an[j] = anch[((size_t)n*MTOT + idx)*5 + j];
  const float CLIP = 4.135166556742356f;           // log(1000/16)
  float dw = fminf(d[2], CLIP), dh = fminf(d[3], CLIP);
  float x  = d[0]*an[2] + an[0];
  float y  = d[1]*an[3] + an[1];
  float bw = expf(dw)*an[2];
  float bh = expf(dh)*an[3];
  float th = an[4] + d[4]*57.29577951308232f;      // 180/pi
  prop[t*5+0]=x; prop[t*5+1]=y; prop[t*5+2]=bw; prop[t*5+3]=bh; prop[t*5+4]=th;
  score[t] = s;
  validf[t] = (bw >= 4.0f && bh >= 4.0f) ? 1u : 0u;
  area[t] = bw*bh;
  float r = 0.5f*sqrtf(bw*bw + bh*bh);
  xyr[t] = make_float4(x, y, r, 0.0f);
  float ang = th * 0.017453292519943295f;          // pi/180
  float cs = cosf(ang), sn = sinf(ang);
  float hw2 = bw*0.5f, hh2 = bh*0.5f;
  const float sx[4] = {1.f,-1.f,-1.f,1.f};
  const float sy[4] = {1.f,1.f,-1.f,-1.f};
  #pragma unroll
  for (int k = 0; k < 4; ++k) {
    float dxk = sx[k]*hw2, dyk = sy[k]*hh2;
    float cx = (x + cs*dxk) - sn*dyk;
    float cy = (y + sn*dxk) + cs*dyk;
    corn[t*8 + k*2 + 0] = cx;
    corn[t*8 + k*2 + 1] = cy;
  }
}

// ---------------- Sutherland-Hodgman (mirrors reference arithmetic) ----------------
__device__ float quad_inter_area(const float* __restrict__ ca, const float* __restrict__ cb) {
#pragma clang fp contract(off)
  float px[8], py[8];
  int n = 4;
  #pragma unroll
  for (int i = 0; i < 4; ++i) { px[i] = ca[2*i]; py[i] = ca[2*i+1]; }
  for (int e = 0; e < 4; ++e) {
    float p1x = cb[2*e], p1y = cb[2*e+1];
    int e2 = (e+1)&3;
    float dx = cb[2*e2] - p1x, dy = cb[2*e2+1] - p1y;
    float sd[8];
    for (int i = 0; i < n; ++i)
      sd[i] = dx*(py[i]-p1y) - dy*(px[i]-p1x);
    float qx[8], qy[8];
    int m = 0;
    for (int i = 0; i < n; ++i) {
      int nx = (i+1 < n) ? i+1 : 0;
      bool ini = sd[i] >= 0.0f, inn = sd[nx] >= 0.0f;
      if (ini) { qx[m]=px[i]; qy[m]=py[i]; ++m; }
      if (ini != inn) {
        float den = sd[i]-sd[nx];
        float dd = (fabsf(den) < 1e-12f) ? 1e-12f : den;
        float tt = sd[i]/dd;
        qx[m] = px[i] + tt*(px[nx]-px[i]);
        qy[m] = py[i] + tt*(py[nx]-py[i]);
        ++m;
      }
    }
    n = m;
    for (int i = 0; i < n; ++i) { px[i]=qx[i]; py[i]=qy[i]; }
    if (n == 0) break;
  }
  float ssum = 0.0f;
  for (int i = 0; i < n; ++i) {
    int nx = (i+1 < n) ? i+1 : 0;
    ssum += px[i]*py[nx] - px[nx]*py[i];
  }
  return 0.5f*fabsf(ssum);
}

// ---------------- fused circle-test + clip with LDS work queue ----------------
__global__ __launch_bounds__(256) void k_iou(const float4* __restrict__ xyr,
                                             const float* __restrict__ corn,
                                             const float* __restrict__ area,
                                             uint64_t* __restrict__ mask) {
  __shared__ uint32_t q[QCAP];       // 32 KB
  __shared__ uint32_t qcnt;
  int n = blockIdx.x / IOU_BPB;
  int wbase = (blockIdx.x % IOU_BPB) * IOU_WPB;
  int wv = threadIdx.x >> 6, lane = threadIdx.x & 63;
  if (threadIdx.x == 0) qcnt = 0;
  __syncthreads();
  for (int w = wv; w < IOU_WPB; w += 4) {
    int word = wbase + w;
    int i = word >> 4;               // word / NWORDS
    int jb = word & 15;              // word % NWORDS
    if (jb*64 + 63 <= i) continue;   // no j > i in this word
    int j = jb*64 + lane;
    bool hit = false;
    if (j > i && j < KTOP) {
      float4 a = xyr[n*KTOP + i];    // wave-uniform
      float4 b = xyr[n*KTOP + j];    // coalesced 16B/lane
      float dx = a.x - b.x, dy = a.y - b.y;
      float rs = a.z + b.z;
      hit = (dx*dx + dy*dy) <= rs*rs*1.0001f;
    }
    unsigned long long bal = __ballot(hit);
    if (!bal) continue;
    int tot = __popcll(bal);
    int leader = __ffsll(bal) - 1;
    uint32_t base = 0;
    if (lane == leader) base = atomicAdd(&qcnt, (uint32_t)tot);
    base = __shfl(base, leader);
    if (hit) {
      int pos = __popcll(bal & ((1ull << lane) - 1ull));
      q[base + pos] = ((uint32_t)i << 10) | (uint32_t)j;
    }
  }
  __syncthreads();
  uint32_t cnt = qcnt;
  for (uint32_t t = threadIdx.x; t < cnt; t += 256) {
    uint32_t code = q[t];
    int i = code >> 10, j = code & 1023;
    int bi = n*KTOP + i, bj = n*KTOP + j;
    float inter = quad_inter_area(&corn[(size_t)bi*8], &corn[(size_t)bj*8]);
    float uni = (area[bi] + area[bj]) - inter;
    if (inter / fmaxf(uni, 1e-8f) > NMS_TH)
      atomicOr((unsigned long long*)&mask[((size_t)n*KTOP + i)*NWORDS + (j>>6)],
               1ull << (j & 63));
  }
}

// ---------------- blocked greedy NMS ----------------
// 16 diagonal blocks of 64 rows. Wave 0 serially resolves the 64x64 diagonal
// (registers + readlane, ~6cy/step); then all 4 waves apply the block's final
// alive rows to later column words via a 64-lane OR-reduction (commutative).
__global__ __launch_bounds__(256) void k_nms(const uint32_t* __restrict__ validf,
                                             const uint64_t* __restrict__ mask,
                                             uint64_t* __restrict__ keep) {
  __shared__ uint64_t kw[NWORDS];
  int n = blockIdx.x;
  int wv = threadIdx.x >> 6, lane = threadIdx.x & 63;
  const uint64_t* M = &mask[(size_t)n*KTOP*NWORDS];

  if (wv == 0) {
    #pragma unroll
    for (int w = 0; w < NWORDS; ++w) {
      int k = w*64 + lane;
      uint32_t v = (k < KTOP) ? validf[n*KTOP + k] : 0u;
      unsigned long long b = __ballot(v != 0u);
      if (lane == 0) kw[w] = (uint64_t)b;
    }
  }
  __syncthreads();

  for (int b = 0; b < NWORDS; ++b) {
    // --- diagonal resolve (wave 0) ---
    if (wv == 0) {
      int row = b*64 + lane;
      uint64_t diag = (row < KTOP) ? M[(size_t)row*NWORDS + b] : 0ull;
      uint64_t alive = kw[b];
      #pragma unroll
      for (int i = 0; i < 64; ++i) {
        uint64_t d = __shfl(diag, i);           // mask[b*64+i][b]: only bits j>i set
        alive &= ~(((alive >> i) & 1ull) ? d : 0ull);
      }
      if (lane == 0) kw[b] = alive;
    }
    __syncthreads();
    if (b == NWORDS-1) break;
    uint64_t alive = kw[b];
    // --- cross-block apply: words l in (b, NWORDS), 4 waves round-robin ---
    int row = b*64 + lane;
    bool me = ((alive >> lane) & 1ull) && (row < KTOP);
    uint64_t mv0=0, mv1=0, mv2=0, mv3=0;
    int l0 = b+1+wv, l1 = l0+4, l2 = l0+8, l3 = l0+12;
    if (me) {
      if (l0 < NWORDS) mv0 = M[(size_t)row*NWORDS + l0];
      if (l1 < NWORDS) mv1 = M[(size_t)row*NWORDS + l1];
      if (l2 < NWORDS) mv2 = M[(size_t)row*NWORDS + l2];
      if (l3 < NWORDS) mv3 = M[(size_t)row*NWORDS + l3];
    }
    #pragma unroll
    for (int s = 1; s < 64; s <<= 1) {
      mv0 |= __shfl_xor(mv0, s);
      mv1 |= __shfl_xor(mv1, s);
      mv2 |= __shfl_xor(mv2, s);
      mv3 |= __shfl_xor(mv3, s);
    }
    if (lane == 0) {
      if (l0 < NWORDS) kw[l0] &= ~mv0;
      if (l1 < NWORDS) kw[l1] &= ~mv1;
      if (l2 < NWORDS) kw[l2] &= ~mv2;
      if (l3 < NWORDS) kw[l3] &= ~mv3;
    }
    __syncthreads();
  }

  if (threadIdx.x == 0) {
    int prev = 0;
    for (int t = 0; t < NWORDS; ++t) {
      uint64_t wrd = kw[t];
      int pc = __popcll(wrd);
      if (prev >= POSTN) wrd = 0;
      else if (prev + pc > POSTN) {
        int allow = POSTN - prev;
        while (__popcll(wrd) > allow) wrd &= ~(1ull << (63 - __clzll(wrd)));
      }
      prev += __popcll(wrd);
      keep[n*NWORDS + t] = wrd;
    }
  }
}

__global__ void k_out(const float* __restrict__ prop, const float* __restrict__ score,
                      const uint64_t* __restrict__ keep, float* __restrict__ out) {
  int t = blockIdx.x*blockDim.x + threadIdx.x;
  if (t >= NBATCH*KTOP) return;
  int n = t / KTOP, k = t % KTOP;
  bool b = (keep[n*NWORDS + (k>>6)] >> (k&63)) & 1ull;
  float f = b ? 1.0f : 0.0f;
  #pragma unroll
  for (int c = 0; c < 5; ++c) out[t*6 + c] = prop[t*5 + c] * f;
  out[t*6 + 5] = score[t] * f;
}

extern "C" void kernel_launch(void* const* d_in, const int* in_sizes, int n_in,
                              void* d_out, int out_size, void* d_ws, size_t ws_size,
                              hipStream_t stream) {
  const float* obj  = (const float*)d_in[0];
  const float* breg = (const float*)d_in[1];
  const float* anch = (const float*)d_in[2];
  float* out = (float*)d_out;
  char* ws = (char*)d_ws;

  uint32_t* hist  = (uint32_t*)(ws + OFF_HIST);
  uint32_t* cnt   = (uint32_t*)(ws + OFF_CNT);
  uint32_t* thr   = (uint32_t*)(ws + OFF_THR);
  uint64_t* cand  = (uint64_t*)(ws + OFF_CAND);
  uint64_t* topk  = (uint64_t*)(ws + OFF_TOPK);
  float*    prop  = (float*)(ws + OFF_PROP);
  float*    score = (float*)(ws + OFF_SCORE);
  float*    corn  = (float*)(ws + OFF_CORN);
  float*    area  = (float*)(ws + OFF_AREA);
  uint32_t* validf= (uint32_t*)(ws + OFF_VALID);
  float4*   xyr   = (float4*)(ws + OFF_XYR);
  uint64_t* mask  = (uint64_t*)(ws + OFF_MASK);
  uint64_t* keep  = (uint64_t*)(ws + OFF_KEEP);

  hipMemsetAsync(ws, 0, OFF_CAND, stream);            // hist + cnt + thr
  hipMemsetAsync(ws + OFF_MASK, 0, SZ_MASK, stream);  // suppression mask

  int nt = NBATCH*MTOT;
  k_hist   <<<NBATCH*BPB, 256, 0, stream>>>(obj, hist);
  k_thresh <<<NBATCH, 256, 0, stream>>>(hist, thr);
  k_compact<<<(nt+255)/256, 256, 0, stream>>>(obj, thr, cand, cnt);
  k_sort   <<<NBATCH, 1024, 0, stream>>>(cand, cnt, topk);
  k_decode <<<(NBATCH*KTOP+255)/256, 256, 0, stream>>>(breg, anch, topk, prop, score, corn, area, xyr, validf);
  k_iou    <<<NBATCH*IOU_BPB, 256, 0, stream>>>(xyr, corn, area, mask);
  k_nms    <<<NBATCH, 256, 0, stream>>>(validf, mask, keep);
  k_out    <<<(NBATCH*KTOP+255)/256, 256, 0, stream>>>(prop, score, keep, out);
}